// Round 5
// baseline (1648.805 us; speedup 1.0000x reference)
//
#include <hip/hip_runtime.h>

#define HDIM 64
#define EPSBN 1e-5f

// ---------------- degree count / dinv ----------------
__global__ void count_edges_k(const int* __restrict__ col, int* __restrict__ cnt, int E) {
    int e = blockIdx.x * blockDim.x + threadIdx.x;
    if (e < E) atomicAdd(&cnt[col[e]], 1);
}

__global__ void dinv_k(const int* __restrict__ cnt, float* __restrict__ dinv, int n) {
    int i = blockIdx.x * blockDim.x + threadIdx.x;
    if (i < n) dinv[i] = rsqrtf((float)cnt[i] + 1.0f);   // +1 for self-loop
}

// ---------------- exclusive scan of cnt -> offs (3-phase) ----------------
__global__ void scan_partial_k(const int* __restrict__ cnt, int* __restrict__ offs,
                               int* __restrict__ bsum, int n) {
    __shared__ int lds[256];
    int tid = threadIdx.x;
    int base = blockIdx.x * 1024 + tid * 4;
    int v0 = (base + 0 < n) ? cnt[base + 0] : 0;
    int v1 = (base + 1 < n) ? cnt[base + 1] : 0;
    int v2 = (base + 2 < n) ? cnt[base + 2] : 0;
    int v3 = (base + 3 < n) ? cnt[base + 3] : 0;
    int tsum = v0 + v1 + v2 + v3;
    lds[tid] = tsum;
    __syncthreads();
    for (int off = 1; off < 256; off <<= 1) {
        int t = (tid >= off) ? lds[tid - off] : 0;
        __syncthreads();
        lds[tid] += t;
        __syncthreads();
    }
    int excl = lds[tid] - tsum;
    if (tid == 255) bsum[blockIdx.x] = lds[255];
    int run = excl;
    if (base + 0 < n) { offs[base + 0] = run; } run += v0;
    if (base + 1 < n) { offs[base + 1] = run; } run += v1;
    if (base + 2 < n) { offs[base + 2] = run; } run += v2;
    if (base + 3 < n) { offs[base + 3] = run; }
}

__global__ void scan_roots_k(int* __restrict__ bsum, int nb) {
    __shared__ int lds[256];
    int tid = threadIdx.x;
    int v = (tid < nb) ? bsum[tid] : 0;
    lds[tid] = v;
    __syncthreads();
    for (int off = 1; off < 256; off <<= 1) {
        int t = (tid >= off) ? lds[tid - off] : 0;
        __syncthreads();
        lds[tid] += t;
        __syncthreads();
    }
    if (tid < nb) bsum[tid] = lds[tid] - v;   // exclusive
}

__global__ void scan_add_k(int* __restrict__ offs, const int* __restrict__ bsum,
                           int* __restrict__ cursor, int n, int Etot) {
    int i = blockIdx.x * blockDim.x + threadIdx.x;
    if (i < n) {
        int o = offs[i] + bsum[i >> 10];
        offs[i] = o;
        cursor[i] = o;
    }
    if (i == 0) offs[n] = Etot;
}

// ---------------- CSR fill, XCD-ownership (kills 8x write amplification) ----------------
__global__ void fill_csr_k(const int* __restrict__ row, const int* __restrict__ col,
                           const float* __restrict__ dinv, int* __restrict__ cursor,
                           int2* __restrict__ srcw, int E, int N) {
    int xcd = blockIdx.x & 7;
    int chunk = blockIdx.x >> 3;
    int e = chunk * 256 + threadIdx.x;
    if (e >= E) return;
    int c = col[e];
    int owner = (int)(((unsigned long long)c * 8ull) / (unsigned)N);
    if (owner != xcd) return;
    int r = row[e];
    float w = dinv[r] * dinv[c];
    int pos = atomicAdd(&cursor[c], 1);
    srcw[pos] = make_int2(r, __float_as_int(w));
}

// ---------------- pad x [N][26] -> xp [N][32] (zeros beyond 26) ----------------
__global__ void pad_x_k(const float* __restrict__ x, float* __restrict__ xp,
                        int N, int INR) {
    int idx = blockIdx.x * blockDim.x + threadIdx.x;
    if (idx >= N * 32) return;
    int i = idx >> 5, k = idx & 31;
    xp[idx] = (k < INR) ? x[i * INR + k] : 0.f;
}

// ---------------- fused conv, tile version ----------------
// Block owns T=16 nodes (contiguous CSR edge range). Phases:
//  1) stage edge chunk (src, w, local tgt via binary search) into LDS — coalesced
//  2) gather-accumulate into LDS agg with ds_add_f32; iterations INDEPENDENT
//     (edge k = s*Q+it spreads the EPI edges of one instr across the tile ->
//      different targets -> few atomic conflicts; agg rows padded to spread banks)
//  3) per-node dense (W col in VGPRs, agg broadcast from LDS) + BN + ReLU
template <int KIN>
__global__ __launch_bounds__(256) void conv_tile_k(
    const float* __restrict__ hin, const int* __restrict__ offs,
    const int2* __restrict__ srcw, const float* __restrict__ dinv,
    const float* __restrict__ W, int KINR,
    const float* __restrict__ bias, const float* __restrict__ g,
    const float* __restrict__ bb, const float* __restrict__ m,
    const float* __restrict__ v, float* __restrict__ hout, int n) {
    constexpr int LPE = KIN / 4;      // lanes per edge
    constexpr int EPI = 64 / LPE;     // edges per gather instruction
    constexpr int T = 16;             // nodes per block
    constexpr int CAP = 512;          // edges per LDS chunk
    constexpr int APAD = KIN + 4;     // padded agg row stride (multiple of 4 words)

    __shared__ float agg[T * APAD];
    __shared__ int4  ebuf[CAP];
    __shared__ int   soffs[T + 1];

    const int tid = threadIdx.x;
    const int wv = tid >> 6, lane = tid & 63;
    const int s = lane / LPE, p = lane % LPE;
    const int i0 = blockIdx.x * T;

    float wreg[KIN];
#pragma unroll
    for (int k = 0; k < KIN; k++) wreg[k] = (k < KINR) ? W[k * HDIM + lane] : 0.f;
    const float sc = g[lane] * rsqrtf(v[lane] + EPSBN);
    const float sh = (bias[lane] - m[lane]) * sc + bb[lane];

    if (tid <= T) {
        int idx = i0 + tid;
        soffs[tid] = offs[idx < n ? idx : n];
    }
    // init agg with self-loop term
    {
        int j = wv * 4;
        for (int jj = j; jj < j + 4; jj++) {
            int i = i0 + jj;
            if (i < n && lane < KIN) {
                float di = dinv[i];
                agg[jj * APAD + lane] = di * di * hin[(size_t)i * KIN + lane];
            }
        }
    }
    __syncthreads();

    const int eBase = soffs[0], eEnd = soffs[T];
    for (int cb = eBase; cb < eEnd; cb += CAP) {
        const int M = min(CAP, eEnd - cb);
        // stage edges + local target
        for (int k = tid; k < M; k += 256) {
            int2 sw = srcw[cb + k];
            int ge = cb + k;
            int lo = 0, hi = T;
            while (hi - lo > 1) { int mid = (lo + hi) >> 1; if (soffs[mid] <= ge) lo = mid; else hi = mid; }
            ebuf[k] = make_int4(sw.x, sw.y, lo, 0);
        }
        __syncthreads();
        // gather-accumulate: independent iterations, many gathers in flight
        const int Q = (M + EPI - 1) / EPI;
        for (int it = wv; it < Q; it += 4) {
            int k = s * Q + it;
            if (k < M) {
                int4 e = ebuf[k];
                const float4 h4 = *(const float4*)(hin + (size_t)e.x * KIN + 4 * p);
                float w = __int_as_float(e.y);
                float* arow = &agg[e.z * APAD + 4 * p];
                atomicAdd(arow + 0, w * h4.x);
                atomicAdd(arow + 1, w * h4.y);
                atomicAdd(arow + 2, w * h4.z);
                atomicAdd(arow + 3, w * h4.w);
            }
        }
        __syncthreads();
    }

    // dense + BN + ReLU, wave per node (4 nodes per wave)
    for (int j = wv; j < T; j += 4) {
        int i = i0 + j;
        if (i >= n) continue;
        const float4* av = (const float4*)&agg[j * APAD];
        float d0 = 0.f, d1 = 0.f, d2 = 0.f, d3 = 0.f;
#pragma unroll
        for (int k4 = 0; k4 < KIN / 4; k4++) {
            float4 a = av[k4];
            d0 = fmaf(a.x, wreg[4 * k4 + 0], d0);
            d1 = fmaf(a.y, wreg[4 * k4 + 1], d1);
            d2 = fmaf(a.z, wreg[4 * k4 + 2], d2);
            d3 = fmaf(a.w, wreg[4 * k4 + 3], d3);
        }
        float dot = (d0 + d1) + (d2 + d3);
        hout[(size_t)i * HDIM + lane] = fmaxf(fmaf(dot, sc, sh), 0.f);
    }
}

// ---------------- pooling (4 waves per graph) + 2-layer MLP ----------------
__global__ __launch_bounds__(256) void pool_mlp_k(
    const float* __restrict__ h, const int* __restrict__ batch,
    const float* __restrict__ Wc1, const float* __restrict__ bc1,
    const float* __restrict__ Wc2, const float* __restrict__ bc2,
    float* __restrict__ out, int n) {
    int gidx = blockIdx.x;
    int tid = threadIdx.x;
    int lane = tid & 63;
    int wv = tid >> 6;

    int lo = 0, hi = n;
    while (lo < hi) { int mid = (lo + hi) >> 1; if (batch[mid] < gidx) lo = mid + 1; else hi = mid; }
    int start = lo;
    lo = start; hi = n;
    while (lo < hi) { int mid = (lo + hi) >> 1; if (batch[mid] <= gidx) lo = mid + 1; else hi = mid; }
    int end = lo;

    float sum = 0.f, mx = 0.f;   // h >= 0 post-ReLU
    for (int i = start + wv; i < end; i += 4) {
        float val = h[(size_t)i * HDIM + lane];
        sum += val;
        mx = fmaxf(mx, val);
    }
    __shared__ float ssum[4 * HDIM];
    __shared__ float smax[4 * HDIM];
    __shared__ float pooled[2 * HDIM];
    ssum[wv * HDIM + lane] = sum;
    smax[wv * HDIM + lane] = mx;
    __syncthreads();
    if (wv == 0) {
        float sv = ssum[lane] + ssum[64 + lane] + ssum[128 + lane] + ssum[192 + lane];
        float mm = fmaxf(fmaxf(smax[lane], smax[64 + lane]),
                         fmaxf(smax[128 + lane], smax[192 + lane]));
        int cnt = end - start;
        pooled[lane] = sv / fmaxf((float)cnt, 1.f);
        pooled[HDIM + lane] = mm;
    }
    __syncthreads();
    if (wv == 0) {
        float a = bc1[lane];
#pragma unroll
        for (int k = 0; k < 2 * HDIM; k++) a = fmaf(pooled[k], Wc1[k * HDIM + lane], a);
        a = fmaxf(a, 0.f);
#pragma unroll
        for (int c = 0; c < 2; c++) {
            float vv = a * Wc2[lane * 2 + c];
            for (int off = 32; off; off >>= 1) vv += __shfl_down(vv, off);
            if (lane == 0) out[gidx * 2 + c] = vv + bc2[c];
        }
    }
}

extern "C" void kernel_launch(void* const* d_in, const int* in_sizes, int n_in,
                              void* d_out, int out_size, void* d_ws, size_t ws_size,
                              hipStream_t stream) {
    const float* x    = (const float*)d_in[0];
    const int*   erow = (const int*)d_in[1];
    const int*   ecol = (const int*)d_in[2];
    const int*   batch= (const int*)d_in[3];
    const float* W0   = (const float*)d_in[4];
    const float* b0   = (const float*)d_in[5];
    const float* W1   = (const float*)d_in[6];
    const float* b1   = (const float*)d_in[7];
    const float* W2   = (const float*)d_in[8];
    const float* b2   = (const float*)d_in[9];
    const float* bn_g = (const float*)d_in[10];
    const float* bn_b = (const float*)d_in[11];
    const float* bn_m = (const float*)d_in[12];
    const float* bn_v = (const float*)d_in[13];
    const float* Wc1  = (const float*)d_in[14];
    const float* bc1  = (const float*)d_in[15];
    const float* Wc2  = (const float*)d_in[16];
    const float* bc2  = (const float*)d_in[17];
    float* out = (float*)d_out;

    const int N = in_sizes[3];
    const int E = in_sizes[1];
    const int G = out_size / 2;
    const int INR = in_sizes[0] / N;    // 26

    char* ws = (char*)d_ws;
    size_t off = 0;
    auto alloc = [&](size_t bytes) -> void* {
        void* p = ws + off;
        off += (bytes + 255) & ~(size_t)255;
        return p;
    };
    int*   cnt    = (int*)alloc((size_t)N * 4);
    float* dinv   = (float*)alloc((size_t)N * 4);
    int*   offs   = (int*)alloc((size_t)(N + 1) * 4);
    int*   cursor = (int*)alloc((size_t)N * 4);
    int*   bsum   = (int*)alloc(1024);
    int2*  srcw   = (int2*)alloc((size_t)E * 8);
    float* bufA   = (float*)alloc((size_t)N * HDIM * 4);
    float* bufB   = (float*)alloc((size_t)N * HDIM * 4);  // doubles as xp [N][32]
    (void)ws_size;

    // ---- build gcn_norm + CSR transpose ----
    hipMemsetAsync(cnt, 0, (size_t)N * 4, stream);
    count_edges_k<<<(E + 255) / 256, 256, 0, stream>>>(ecol, cnt, E);
    dinv_k<<<(N + 255) / 256, 256, 0, stream>>>(cnt, dinv, N);
    int nb = (N + 1023) / 1024;
    scan_partial_k<<<nb, 256, 0, stream>>>(cnt, offs, bsum, N);
    scan_roots_k<<<1, 256, 0, stream>>>(bsum, nb);
    scan_add_k<<<(N + 255) / 256, 256, 0, stream>>>(offs, bsum, cursor, N, E);
    int chunks = (E + 255) / 256;
    fill_csr_k<<<chunks * 8, 256, 0, stream>>>(erow, ecol, dinv, cursor, srcw, E, N);

    // ---- pad x into bufB [N][32] ----
    pad_x_k<<<(N * 32 + 255) / 256, 256, 0, stream>>>(x, bufB, N, INR);

    int cgrid = (N + 15) / 16;
    // ---- layer 0: KIN=32 (padded 26), bufB(xp) -> bufA ----
    conv_tile_k<32><<<cgrid, 256, 0, stream>>>(bufB, offs, srcw, dinv, W0, INR, b0,
                                               bn_g + 0, bn_b + 0, bn_m + 0, bn_v + 0, bufA, N);
    // ---- layer 1: bufA -> bufB ----
    conv_tile_k<64><<<cgrid, 256, 0, stream>>>(bufA, offs, srcw, dinv, W1, 64, b1,
                                               bn_g + 64, bn_b + 64, bn_m + 64, bn_v + 64, bufB, N);
    // ---- layer 2: bufB -> bufA ----
    conv_tile_k<64><<<cgrid, 256, 0, stream>>>(bufB, offs, srcw, dinv, W2, 64, b2,
                                               bn_g + 128, bn_b + 128, bn_m + 128, bn_v + 128, bufA, N);

    // ---- pool + MLP ----
    pool_mlp_k<<<G, 256, 0, stream>>>(bufA, batch, Wc1, bc1, Wc2, bc2, out, N);
}

// Round 6
// 781.584 us; speedup vs baseline: 2.1096x; 2.1096x over previous
//
#include <hip/hip_runtime.h>

#define HDIM 64
#define EPSBN 1e-5f

// ---------------- degree count / dinv ----------------
__global__ void count_edges_k(const int* __restrict__ col, int* __restrict__ cnt, int E) {
    int e = blockIdx.x * blockDim.x + threadIdx.x;
    if (e < E) atomicAdd(&cnt[col[e]], 1);
}

__global__ void dinv_k(const int* __restrict__ cnt, float* __restrict__ dinv, int n) {
    int i = blockIdx.x * blockDim.x + threadIdx.x;
    if (i < n) dinv[i] = rsqrtf((float)cnt[i] + 1.0f);   // +1 for self-loop
}

// ---------------- exclusive scan of cnt -> offs (3-phase) ----------------
__global__ void scan_partial_k(const int* __restrict__ cnt, int* __restrict__ offs,
                               int* __restrict__ bsum, int n) {
    __shared__ int lds[256];
    int tid = threadIdx.x;
    int base = blockIdx.x * 1024 + tid * 4;
    int v0 = (base + 0 < n) ? cnt[base + 0] : 0;
    int v1 = (base + 1 < n) ? cnt[base + 1] : 0;
    int v2 = (base + 2 < n) ? cnt[base + 2] : 0;
    int v3 = (base + 3 < n) ? cnt[base + 3] : 0;
    int tsum = v0 + v1 + v2 + v3;
    lds[tid] = tsum;
    __syncthreads();
    for (int off = 1; off < 256; off <<= 1) {
        int t = (tid >= off) ? lds[tid - off] : 0;
        __syncthreads();
        lds[tid] += t;
        __syncthreads();
    }
    int excl = lds[tid] - tsum;
    if (tid == 255) bsum[blockIdx.x] = lds[255];
    int run = excl;
    if (base + 0 < n) { offs[base + 0] = run; } run += v0;
    if (base + 1 < n) { offs[base + 1] = run; } run += v1;
    if (base + 2 < n) { offs[base + 2] = run; } run += v2;
    if (base + 3 < n) { offs[base + 3] = run; }
}

__global__ void scan_roots_k(int* __restrict__ bsum, int nb) {
    __shared__ int lds[256];
    int tid = threadIdx.x;
    int v = (tid < nb) ? bsum[tid] : 0;
    lds[tid] = v;
    __syncthreads();
    for (int off = 1; off < 256; off <<= 1) {
        int t = (tid >= off) ? lds[tid - off] : 0;
        __syncthreads();
        lds[tid] += t;
        __syncthreads();
    }
    if (tid < nb) bsum[tid] = lds[tid] - v;   // exclusive
}

__global__ void scan_add_k(int* __restrict__ offs, const int* __restrict__ bsum,
                           int* __restrict__ cursor, int n, int Etot) {
    int i = blockIdx.x * blockDim.x + threadIdx.x;
    if (i < n) {
        int o = offs[i] + bsum[i >> 10];
        offs[i] = o;
        cursor[i] = o;
    }
    if (i == 0) offs[n] = Etot;
}

// ---------------- CSR fill, XCD-ownership (kills 8x write amplification) ----------------
__global__ void fill_csr_k(const int* __restrict__ row, const int* __restrict__ col,
                           const float* __restrict__ dinv, int* __restrict__ cursor,
                           int2* __restrict__ srcw, int E, int N) {
    int xcd = blockIdx.x & 7;
    int chunk = blockIdx.x >> 3;
    int e = chunk * 256 + threadIdx.x;
    if (e >= E) return;
    int c = col[e];
    int owner = (int)(((unsigned long long)c * 8ull) / (unsigned)N);
    if (owner != xcd) return;
    int r = row[e];
    float w = dinv[r] * dinv[c];
    int pos = atomicAdd(&cursor[c], 1);
    srcw[pos] = make_int2(r, __float_as_int(w));
}

// ---------------- pad x [N][26] -> xp [N][32] (zeros beyond 26) ----------------
__global__ void pad_x_k(const float* __restrict__ x, float* __restrict__ xp,
                        int N, int INR) {
    int idx = blockIdx.x * blockDim.x + threadIdx.x;
    if (idx >= N * 32) return;
    int i = idx >> 5, k = idx & 31;
    xp[idx] = (k < INR) ? x[i * INR + k] : 0.f;
}

// ---------------- fused conv: batched-gather aggregate + dense + BN + ReLU ----------------
// Block = 256 (4 waves), 16 nodes/block, 4 nodes/wave (register accumulation).
// Gather phase per node: groups of 8 gather instructions. srcw indices for the
// group are wave-uniform consecutive -> 8 scalar loads (compiler merges to
// s_load_dwordx8/16), then 8 INDEPENDENT vector gathers in flight, then 8 FMAs.
// Out-of-range slots gather the node's own row (L1-hot) with w=0 -> branchless,
// no extra HBM traffic. KIN=32: 2 edges per gather instruction (slot = lane/32),
// shfl_xor(32) combines slots; self term added in slot 0 only.
// Epilogue: single barrier-separated LDS transpose (no exec-mask race), then
// dense with W column in VGPRs (loaded after gather phase to cap VGPR pressure).
template <int KIN>
__global__ __launch_bounds__(256, 4) void conv_k(
    const float* __restrict__ hin, const int* __restrict__ offs,
    const int2* __restrict__ srcw, const float* __restrict__ dinv,
    const float* __restrict__ W, int KINR,
    const float* __restrict__ bias, const float* __restrict__ g,
    const float* __restrict__ bb, const float* __restrict__ m,
    const float* __restrict__ v, float* __restrict__ hout, int n) {
    constexpr int SLOTS = 64 / KIN;  // 1 (KIN=64) or 2 (KIN=32)
    constexpr int NPW = 4;           // nodes per wave
    const int tid = threadIdx.x;
    const int wv = tid >> 6, lane = tid & 63;
    const int feat = lane & (KIN - 1);
    const int slot = lane / KIN;
    const int i0 = blockIdx.x * 16;

    __shared__ float aggL[16 * KIN];

    float accv[NPW];
#pragma unroll
    for (int j = 0; j < NPW; j++) {
        const int i = i0 + wv * NPW + j;
        float acc = 0.f;
        if (i < n) {
            const float di = dinv[i];
            const float self = hin[(size_t)i * KIN + feat];   // warms L1 for masked slots
            acc = (slot == 0) ? self * di * di : 0.f;
            const int s0 = offs[i], s1 = offs[i + 1];
            for (int e = s0; e < s1; e += 8 * SLOTS) {
                float hh[8], ww[8];
#pragma unroll
                for (int u = 0; u < 8; u++) {
                    const int eu = e + u * SLOTS;
                    int su; float wu;
                    if (SLOTS == 1) {
                        int2 gg = srcw[eu];                    // uniform -> s_load
                        bool vu = eu < s1;
                        su = vu ? gg.x : i;
                        wu = vu ? __int_as_float(gg.y) : 0.f;
                    } else {
                        int2 ga = srcw[eu];                    // uniform -> s_load
                        int2 gb = srcw[eu + 1];
                        bool va = eu < s1, vb = (eu + 1) < s1;
                        int sa = va ? ga.x : i;
                        float wa = va ? __int_as_float(ga.y) : 0.f;
                        int sb = vb ? gb.x : i;
                        float wb = vb ? __int_as_float(gb.y) : 0.f;
                        su = (slot == 0) ? sa : sb;
                        wu = (slot == 0) ? wa : wb;
                    }
                    ww[u] = wu;
                    hh[u] = hin[(size_t)su * KIN + feat];      // independent gathers
                }
#pragma unroll
                for (int u = 0; u < 8; u++) acc = fmaf(ww[u], hh[u], acc);
            }
            if (SLOTS == 2) acc += __shfl_xor(acc, 32);
        }
        accv[j] = acc;
    }

    // transpose via LDS (barrier-separated; both slots hold identical values for
    // SLOTS=2, only slot 0 writes)
#pragma unroll
    for (int j = 0; j < NPW; j++) {
        if (slot == 0) aggL[(wv * NPW + j) * KIN + feat] = accv[j];
    }
    __syncthreads();

    // epilogue: dense KIN->64 + BN + ReLU
    float wreg[KIN];
#pragma unroll
    for (int k = 0; k < KIN; k++) wreg[k] = (k < KINR) ? W[k * HDIM + lane] : 0.f;
    const float sc = g[lane] * rsqrtf(v[lane] + EPSBN);
    const float sh = (bias[lane] - m[lane]) * sc + bb[lane];
#pragma unroll
    for (int j = 0; j < NPW; j++) {
        const int i = i0 + wv * NPW + j;
        if (i >= n) continue;
        const float4* av = (const float4*)&aggL[(wv * NPW + j) * KIN];
        float d0 = 0.f, d1 = 0.f, d2 = 0.f, d3 = 0.f;
#pragma unroll
        for (int k4 = 0; k4 < KIN / 4; k4++) {
            float4 a = av[k4];   // broadcast LDS read
            d0 = fmaf(a.x, wreg[4 * k4 + 0], d0);
            d1 = fmaf(a.y, wreg[4 * k4 + 1], d1);
            d2 = fmaf(a.z, wreg[4 * k4 + 2], d2);
            d3 = fmaf(a.w, wreg[4 * k4 + 3], d3);
        }
        const float dot = (d0 + d1) + (d2 + d3);
        hout[(size_t)i * HDIM + lane] = fmaxf(fmaf(dot, sc, sh), 0.f);
    }
}

// ---------------- pooling (4 waves per graph) + 2-layer MLP ----------------
__global__ __launch_bounds__(256) void pool_mlp_k(
    const float* __restrict__ h, const int* __restrict__ batch,
    const float* __restrict__ Wc1, const float* __restrict__ bc1,
    const float* __restrict__ Wc2, const float* __restrict__ bc2,
    float* __restrict__ out, int n) {
    int gidx = blockIdx.x;
    int tid = threadIdx.x;
    int lane = tid & 63;
    int wv = tid >> 6;

    int lo = 0, hi = n;
    while (lo < hi) { int mid = (lo + hi) >> 1; if (batch[mid] < gidx) lo = mid + 1; else hi = mid; }
    int start = lo;
    lo = start; hi = n;
    while (lo < hi) { int mid = (lo + hi) >> 1; if (batch[mid] <= gidx) lo = mid + 1; else hi = mid; }
    int end = lo;

    float sum = 0.f, mx = 0.f;   // h >= 0 post-ReLU
    for (int i = start + wv; i < end; i += 4) {
        float val = h[(size_t)i * HDIM + lane];
        sum += val;
        mx = fmaxf(mx, val);
    }
    __shared__ float ssum[4 * HDIM];
    __shared__ float smax[4 * HDIM];
    __shared__ float pooled[2 * HDIM];
    ssum[wv * HDIM + lane] = sum;
    smax[wv * HDIM + lane] = mx;
    __syncthreads();
    if (wv == 0) {
        float sv = ssum[lane] + ssum[64 + lane] + ssum[128 + lane] + ssum[192 + lane];
        float mm = fmaxf(fmaxf(smax[lane], smax[64 + lane]),
                         fmaxf(smax[128 + lane], smax[192 + lane]));
        int cnt = end - start;
        pooled[lane] = sv / fmaxf((float)cnt, 1.f);
        pooled[HDIM + lane] = mm;
    }
    __syncthreads();
    if (wv == 0) {
        float a = bc1[lane];
#pragma unroll
        for (int k = 0; k < 2 * HDIM; k++) a = fmaf(pooled[k], Wc1[k * HDIM + lane], a);
        a = fmaxf(a, 0.f);
#pragma unroll
        for (int c = 0; c < 2; c++) {
            float vv = a * Wc2[lane * 2 + c];
            for (int off = 32; off; off >>= 1) vv += __shfl_down(vv, off);
            if (lane == 0) out[gidx * 2 + c] = vv + bc2[c];
        }
    }
}

extern "C" void kernel_launch(void* const* d_in, const int* in_sizes, int n_in,
                              void* d_out, int out_size, void* d_ws, size_t ws_size,
                              hipStream_t stream) {
    const float* x    = (const float*)d_in[0];
    const int*   erow = (const int*)d_in[1];
    const int*   ecol = (const int*)d_in[2];
    const int*   batch= (const int*)d_in[3];
    const float* W0   = (const float*)d_in[4];
    const float* b0   = (const float*)d_in[5];
    const float* W1   = (const float*)d_in[6];
    const float* b1   = (const float*)d_in[7];
    const float* W2   = (const float*)d_in[8];
    const float* b2   = (const float*)d_in[9];
    const float* bn_g = (const float*)d_in[10];
    const float* bn_b = (const float*)d_in[11];
    const float* bn_m = (const float*)d_in[12];
    const float* bn_v = (const float*)d_in[13];
    const float* Wc1  = (const float*)d_in[14];
    const float* bc1  = (const float*)d_in[15];
    const float* Wc2  = (const float*)d_in[16];
    const float* bc2  = (const float*)d_in[17];
    float* out = (float*)d_out;

    const int N = in_sizes[3];
    const int E = in_sizes[1];
    const int G = out_size / 2;
    const int INR = in_sizes[0] / N;    // 26

    char* ws = (char*)d_ws;
    size_t off = 0;
    auto alloc = [&](size_t bytes) -> void* {
        void* p = ws + off;
        off += (bytes + 255) & ~(size_t)255;
        return p;
    };
    int*   cnt    = (int*)alloc((size_t)N * 4);
    float* dinv   = (float*)alloc((size_t)N * 4);
    int*   offs   = (int*)alloc((size_t)(N + 1) * 4);
    int*   cursor = (int*)alloc((size_t)N * 4);
    int*   bsum   = (int*)alloc(1024);
    int2*  srcw   = (int2*)alloc((size_t)E * 8 + 256);   // +slack for group overread
    float* bufA   = (float*)alloc((size_t)N * HDIM * 4);
    float* bufB   = (float*)alloc((size_t)N * HDIM * 4);  // doubles as xp [N][32]
    (void)ws_size;

    // ---- build gcn_norm + CSR transpose ----
    hipMemsetAsync(cnt, 0, (size_t)N * 4, stream);
    count_edges_k<<<(E + 255) / 256, 256, 0, stream>>>(ecol, cnt, E);
    dinv_k<<<(N + 255) / 256, 256, 0, stream>>>(cnt, dinv, N);
    int nb = (N + 1023) / 1024;
    scan_partial_k<<<nb, 256, 0, stream>>>(cnt, offs, bsum, N);
    scan_roots_k<<<1, 256, 0, stream>>>(bsum, nb);
    scan_add_k<<<(N + 255) / 256, 256, 0, stream>>>(offs, bsum, cursor, N, E);
    int chunks = (E + 255) / 256;
    fill_csr_k<<<chunks * 8, 256, 0, stream>>>(erow, ecol, dinv, cursor, srcw, E, N);

    // ---- pad x into bufB [N][32] ----
    pad_x_k<<<(N * 32 + 255) / 256, 256, 0, stream>>>(x, bufB, N, INR);

    int cgrid = (N + 15) / 16;
    // ---- layer 0: KIN=32 (padded 26), bufB(xp) -> bufA ----
    conv_k<32><<<cgrid, 256, 0, stream>>>(bufB, offs, srcw, dinv, W0, INR, b0,
                                          bn_g + 0, bn_b + 0, bn_m + 0, bn_v + 0, bufA, N);
    // ---- layer 1: bufA -> bufB ----
    conv_k<64><<<cgrid, 256, 0, stream>>>(bufA, offs, srcw, dinv, W1, 64, b1,
                                          bn_g + 64, bn_b + 64, bn_m + 64, bn_v + 64, bufB, N);
    // ---- layer 2: bufB -> bufA ----
    conv_k<64><<<cgrid, 256, 0, stream>>>(bufB, offs, srcw, dinv, W2, 64, b2,
                                          bn_g + 128, bn_b + 128, bn_m + 128, bn_v + 128, bufA, N);

    // ---- pool + MLP ----
    pool_mlp_k<<<G, 256, 0, stream>>>(bufA, batch, Wc1, bc1, Wc2, bc2, out, N);
}

// Round 7
// 496.219 us; speedup vs baseline: 3.3227x; 1.5751x over previous
//
#include <hip/hip_runtime.h>

#define HDIM 64
#define EPSBN 1e-5f
#define MNODES 8

// ---------------- degree count ----------------
__global__ void count_edges_k(const int* __restrict__ col, int* __restrict__ cnt, int E) {
    int e = blockIdx.x * blockDim.x + threadIdx.x;
    if (e < E) atomicAdd(&cnt[col[e]], 1);
}

// ---------------- exclusive scan of cnt -> offs (2 kernels) ----------------
__global__ void scan_partial_k(const int* __restrict__ cnt, int* __restrict__ offs,
                               int* __restrict__ bsum, int n) {
    __shared__ int lds[256];
    int tid = threadIdx.x;
    int base = blockIdx.x * 1024 + tid * 4;
    int v0 = (base + 0 < n) ? cnt[base + 0] : 0;
    int v1 = (base + 1 < n) ? cnt[base + 1] : 0;
    int v2 = (base + 2 < n) ? cnt[base + 2] : 0;
    int v3 = (base + 3 < n) ? cnt[base + 3] : 0;
    int tsum = v0 + v1 + v2 + v3;
    lds[tid] = tsum;
    __syncthreads();
    for (int off = 1; off < 256; off <<= 1) {
        int t = (tid >= off) ? lds[tid - off] : 0;
        __syncthreads();
        lds[tid] += t;
        __syncthreads();
    }
    int excl = lds[tid] - tsum;
    if (tid == 255) bsum[blockIdx.x] = lds[255];
    int run = excl;
    if (base + 0 < n) { offs[base + 0] = run; } run += v0;
    if (base + 1 < n) { offs[base + 1] = run; } run += v1;
    if (base + 2 < n) { offs[base + 2] = run; } run += v2;
    if (base + 3 < n) { offs[base + 3] = run; }
}

// adds block bases (re-scanning the <=256 block sums in-block), writes cursor,
// computes dinv — 3 former kernels in one.
__global__ void scan_add_k(const int* __restrict__ cnt, int* __restrict__ offs,
                           const int* __restrict__ bsum, int nb,
                           int* __restrict__ cursor, float* __restrict__ dinv,
                           int n, int Etot) {
    __shared__ int lds[256];
    int tid = threadIdx.x;
    int v = (tid < nb) ? bsum[tid] : 0;
    lds[tid] = v;
    __syncthreads();
    for (int off = 1; off < 256; off <<= 1) {
        int t = (tid >= off) ? lds[tid - off] : 0;
        __syncthreads();
        lds[tid] += t;
        __syncthreads();
    }
    int excl = lds[tid] - v;
    __syncthreads();
    lds[tid] = excl;          // lds[b] = exclusive prefix of bsum
    __syncthreads();

    int i = blockIdx.x * blockDim.x + tid;
    if (i < n) {
        int o = offs[i] + lds[i >> 10];
        offs[i] = o;
        cursor[i] = o;
        dinv[i] = rsqrtf((float)cnt[i] + 1.0f);   // +1 for self-loop
    }
    if (i == 0) offs[n] = Etot;
}

// ---------------- CSR fill (XCD-ownership) + x padding, fused ----------------
// Fill: each 256-edge chunk visited by 8 blocks (one per XCD via blockIdx%8);
// a block only writes cols in its XCD's node range -> srcw lines produced
// within one XCD's L2 -> no 8x write amplification (R1->R2: 101->~15 MB).
// Pad: first padTot/256 blocks also write xp[N][32] from x[N][26].
__global__ void fillpad_k(const int* __restrict__ row, const int* __restrict__ col,
                          const float* __restrict__ dinv, int* __restrict__ cursor,
                          int2* __restrict__ srcw, int E, int N,
                          const float* __restrict__ x, float* __restrict__ xp,
                          int INR, int padTot) {
    int bid = blockIdx.x, tid = threadIdx.x;
    int pidx = bid * 256 + tid;
    if (pidx < padTot) {
        int i = pidx >> 5, k = pidx & 31;
        xp[pidx] = (k < INR) ? x[i * INR + k] : 0.f;
    }
    int xcd = bid & 7;
    int chunk = bid >> 3;
    int e = chunk * 256 + tid;
    if (e >= E) return;
    int c = col[e];
    int owner = (int)(((unsigned long long)c * 8ull) / (unsigned)N);
    if (owner != xcd) return;
    int r = row[e];
    float w = dinv[r] * dinv[c];
    int pos = atomicAdd(&cursor[c], 1);
    srcw[pos] = make_int2(r, __float_as_int(w));
}

// ---------------- fused conv: aggregate-first + dense + bias + BN + ReLU ----------------
// R2-proven structure: one 64-thread block (1 wave) handles MNODES nodes serially;
// lane = output feature. conv(h) = (segsum(norm*h) + dinv^2*h_self) @ W -> BN -> ReLU.
// Only change vs R2: unmasked 8-wide main gather loop ahead of the 4-wide one.
template <int KIN>
__global__ __launch_bounds__(64) void conv_k(
    const float* __restrict__ hin, const int* __restrict__ offs,
    const int2* __restrict__ srcw, const float* __restrict__ dinv,
    const float* __restrict__ W, int KINR,
    const float* __restrict__ bias, const float* __restrict__ g,
    const float* __restrict__ bb, const float* __restrict__ m,
    const float* __restrict__ v, float* __restrict__ hout, int n) {
    int lane = threadIdx.x;
    float wreg[KIN];                        // W column for this lane
#pragma unroll
    for (int k = 0; k < KIN; k++) wreg[k] = (k < KINR) ? W[k * HDIM + lane] : 0.f;
    const float sc = g[lane] * rsqrtf(v[lane] + EPSBN);
    const float sh = (bias[lane] - m[lane]) * sc + bb[lane];

    __shared__ float agg[KIN];

    int i0 = blockIdx.x * MNODES;
    for (int j = 0; j < MNODES; j++) {
        int i = i0 + j;
        if (i >= n) break;                  // wave-uniform
        float di = dinv[i];
        float acc = 0.f;
        if (lane < KIN) acc = hin[(size_t)i * KIN + lane] * (di * di);  // self-loop
        int e = offs[i], s1 = offs[i + 1];
        for (; e + 8 <= s1; e += 8) {
            int2 sw0 = srcw[e],     sw1 = srcw[e + 1], sw2 = srcw[e + 2], sw3 = srcw[e + 3];
            int2 sw4 = srcw[e + 4], sw5 = srcw[e + 5], sw6 = srcw[e + 6], sw7 = srcw[e + 7];
            float h0 = 0.f, h1 = 0.f, h2 = 0.f, h3 = 0.f;
            float h4 = 0.f, h5 = 0.f, h6 = 0.f, h7 = 0.f;
            if (lane < KIN) {
                h0 = hin[(size_t)sw0.x * KIN + lane];
                h1 = hin[(size_t)sw1.x * KIN + lane];
                h2 = hin[(size_t)sw2.x * KIN + lane];
                h3 = hin[(size_t)sw3.x * KIN + lane];
                h4 = hin[(size_t)sw4.x * KIN + lane];
                h5 = hin[(size_t)sw5.x * KIN + lane];
                h6 = hin[(size_t)sw6.x * KIN + lane];
                h7 = hin[(size_t)sw7.x * KIN + lane];
            }
            acc = fmaf(__int_as_float(sw0.y), h0, acc);
            acc = fmaf(__int_as_float(sw1.y), h1, acc);
            acc = fmaf(__int_as_float(sw2.y), h2, acc);
            acc = fmaf(__int_as_float(sw3.y), h3, acc);
            acc = fmaf(__int_as_float(sw4.y), h4, acc);
            acc = fmaf(__int_as_float(sw5.y), h5, acc);
            acc = fmaf(__int_as_float(sw6.y), h6, acc);
            acc = fmaf(__int_as_float(sw7.y), h7, acc);
        }
        for (; e + 4 <= s1; e += 4) {
            int2 sw0 = srcw[e], sw1 = srcw[e + 1], sw2 = srcw[e + 2], sw3 = srcw[e + 3];
            float h0 = 0.f, h1 = 0.f, h2 = 0.f, h3 = 0.f;
            if (lane < KIN) {
                h0 = hin[(size_t)sw0.x * KIN + lane];
                h1 = hin[(size_t)sw1.x * KIN + lane];
                h2 = hin[(size_t)sw2.x * KIN + lane];
                h3 = hin[(size_t)sw3.x * KIN + lane];
            }
            acc = fmaf(__int_as_float(sw0.y), h0, acc);
            acc = fmaf(__int_as_float(sw1.y), h1, acc);
            acc = fmaf(__int_as_float(sw2.y), h2, acc);
            acc = fmaf(__int_as_float(sw3.y), h3, acc);
        }
        for (; e < s1; e++) {
            int2 sw = srcw[e];
            float hh = (lane < KIN) ? hin[(size_t)sw.x * KIN + lane] : 0.f;
            acc = fmaf(__int_as_float(sw.y), hh, acc);
        }
        __syncthreads();                    // protect agg from previous iteration readers
        if (lane < KIN) agg[lane] = acc;
        __syncthreads();
        float dot = 0.f;
        const float4* aggv = (const float4*)agg;
#pragma unroll
        for (int k4 = 0; k4 < KIN / 4; k4++) {
            float4 a = aggv[k4];
            dot = fmaf(a.x, wreg[4 * k4 + 0], dot);
            dot = fmaf(a.y, wreg[4 * k4 + 1], dot);
            dot = fmaf(a.z, wreg[4 * k4 + 2], dot);
            dot = fmaf(a.w, wreg[4 * k4 + 3], dot);
        }
        float y = fmaf(dot, sc, sh);
        hout[(size_t)i * HDIM + lane] = fmaxf(y, 0.f);
    }
}

// ---------------- pooling (4 waves per graph) + 2-layer MLP ----------------
__global__ __launch_bounds__(256) void pool_mlp_k(
    const float* __restrict__ h, const int* __restrict__ batch,
    const float* __restrict__ Wc1, const float* __restrict__ bc1,
    const float* __restrict__ Wc2, const float* __restrict__ bc2,
    float* __restrict__ out, int n) {
    int gidx = blockIdx.x;
    int tid = threadIdx.x;
    int lane = tid & 63;
    int wv = tid >> 6;

    int lo = 0, hi = n;
    while (lo < hi) { int mid = (lo + hi) >> 1; if (batch[mid] < gidx) lo = mid + 1; else hi = mid; }
    int start = lo;
    lo = start; hi = n;
    while (lo < hi) { int mid = (lo + hi) >> 1; if (batch[mid] <= gidx) lo = mid + 1; else hi = mid; }
    int end = lo;

    float sum = 0.f, mx = 0.f;   // h >= 0 post-ReLU
    for (int i = start + wv; i < end; i += 4) {
        float val = h[(size_t)i * HDIM + lane];
        sum += val;
        mx = fmaxf(mx, val);
    }
    __shared__ float ssum[4 * HDIM];
    __shared__ float smax[4 * HDIM];
    __shared__ float pooled[2 * HDIM];
    ssum[wv * HDIM + lane] = sum;
    smax[wv * HDIM + lane] = mx;
    __syncthreads();
    if (wv == 0) {
        float sv = ssum[lane] + ssum[64 + lane] + ssum[128 + lane] + ssum[192 + lane];
        float mm = fmaxf(fmaxf(smax[lane], smax[64 + lane]),
                         fmaxf(smax[128 + lane], smax[192 + lane]));
        int cnt = end - start;
        pooled[lane] = sv / fmaxf((float)cnt, 1.f);
        pooled[HDIM + lane] = mm;
    }
    __syncthreads();
    if (wv == 0) {
        float a = bc1[lane];
#pragma unroll
        for (int k = 0; k < 2 * HDIM; k++) a = fmaf(pooled[k], Wc1[k * HDIM + lane], a);
        a = fmaxf(a, 0.f);
#pragma unroll
        for (int c = 0; c < 2; c++) {
            float vv = a * Wc2[lane * 2 + c];
            for (int off = 32; off; off >>= 1) vv += __shfl_down(vv, off);
            if (lane == 0) out[gidx * 2 + c] = vv + bc2[c];
        }
    }
}

extern "C" void kernel_launch(void* const* d_in, const int* in_sizes, int n_in,
                              void* d_out, int out_size, void* d_ws, size_t ws_size,
                              hipStream_t stream) {
    const float* x    = (const float*)d_in[0];
    const int*   erow = (const int*)d_in[1];
    const int*   ecol = (const int*)d_in[2];
    const int*   batch= (const int*)d_in[3];
    const float* W0   = (const float*)d_in[4];
    const float* b0   = (const float*)d_in[5];
    const float* W1   = (const float*)d_in[6];
    const float* b1   = (const float*)d_in[7];
    const float* W2   = (const float*)d_in[8];
    const float* b2   = (const float*)d_in[9];
    const float* bn_g = (const float*)d_in[10];
    const float* bn_b = (const float*)d_in[11];
    const float* bn_m = (const float*)d_in[12];
    const float* bn_v = (const float*)d_in[13];
    const float* Wc1  = (const float*)d_in[14];
    const float* bc1  = (const float*)d_in[15];
    const float* Wc2  = (const float*)d_in[16];
    const float* bc2  = (const float*)d_in[17];
    float* out = (float*)d_out;

    const int N = in_sizes[3];
    const int E = in_sizes[1];
    const int G = out_size / 2;
    const int INR = in_sizes[0] / N;    // 26

    char* ws = (char*)d_ws;
    size_t off = 0;
    auto alloc = [&](size_t bytes) -> void* {
        void* p = ws + off;
        off += (bytes + 255) & ~(size_t)255;
        return p;
    };
    int*   cnt    = (int*)alloc((size_t)N * 4);
    float* dinv   = (float*)alloc((size_t)N * 4);
    int*   offs   = (int*)alloc((size_t)(N + 1) * 4);
    int*   cursor = (int*)alloc((size_t)N * 4);
    int*   bsum   = (int*)alloc(1024);
    int2*  srcw   = (int2*)alloc((size_t)E * 8 + 256);
    float* bufA   = (float*)alloc((size_t)N * HDIM * 4);
    float* bufB   = (float*)alloc((size_t)N * HDIM * 4);  // doubles as xp [N][32]
    (void)ws_size;

    // ---- build gcn_norm + CSR transpose ----
    hipMemsetAsync(cnt, 0, (size_t)N * 4, stream);
    count_edges_k<<<(E + 255) / 256, 256, 0, stream>>>(ecol, cnt, E);
    int nb = (N + 1023) / 1024;
    scan_partial_k<<<nb, 256, 0, stream>>>(cnt, offs, bsum, N);
    scan_add_k<<<(N + 255) / 256, 256, 0, stream>>>(cnt, offs, bsum, nb, cursor, dinv, N, E);
    int chunks = (E + 255) / 256;
    fillpad_k<<<chunks * 8, 256, 0, stream>>>(erow, ecol, dinv, cursor, srcw, E, N,
                                              x, bufB, INR, N * 32);

    int cgrid = (N + MNODES - 1) / MNODES;
    // ---- layer 0: KIN=32 (padded 26), bufB(xp) -> bufA ----
    conv_k<32><<<cgrid, 64, 0, stream>>>(bufB, offs, srcw, dinv, W0, INR, b0,
                                         bn_g + 0, bn_b + 0, bn_m + 0, bn_v + 0, bufA, N);
    // ---- layer 1: bufA -> bufB ----
    conv_k<64><<<cgrid, 64, 0, stream>>>(bufA, offs, srcw, dinv, W1, 64, b1,
                                         bn_g + 64, bn_b + 64, bn_m + 64, bn_v + 64, bufB, N);
    // ---- layer 2: bufB -> bufA ----
    conv_k<64><<<cgrid, 64, 0, stream>>>(bufB, offs, srcw, dinv, W2, 64, b2,
                                         bn_g + 128, bn_b + 128, bn_m + 128, bn_v + 128, bufA, N);

    // ---- pool + MLP ----
    pool_mlp_k<<<G, 256, 0, stream>>>(bufA, batch, Wc1, bc1, Wc2, bc2, out, N);
}

// Round 8
// 489.278 us; speedup vs baseline: 3.3699x; 1.0142x over previous
//
#include <hip/hip_runtime.h>

#define HDIM 64
#define EPSBN 1e-5f
#define MNODES 8

typedef unsigned short u16;

__device__ __forceinline__ float bf2f(u16 b) {
    return __uint_as_float(((unsigned)b) << 16);
}
__device__ __forceinline__ u16 f2bf_rne(float f) {
    unsigned u = __float_as_uint(f);
    u += 0x7FFFu + ((u >> 16) & 1u);      // round-to-nearest-even
    return (u16)(u >> 16);
}

// ---------------- degree count ----------------
__global__ void count_edges_k(const int* __restrict__ col, int* __restrict__ cnt, int E) {
    int e = blockIdx.x * blockDim.x + threadIdx.x;
    if (e < E) atomicAdd(&cnt[col[e]], 1);
}

// ---------------- exclusive scan of cnt -> offs ----------------
__global__ void scan_partial_k(const int* __restrict__ cnt, int* __restrict__ offs,
                               int* __restrict__ bsum, int n) {
    __shared__ int lds[256];
    int tid = threadIdx.x;
    int base = blockIdx.x * 1024 + tid * 4;
    int v0 = (base + 0 < n) ? cnt[base + 0] : 0;
    int v1 = (base + 1 < n) ? cnt[base + 1] : 0;
    int v2 = (base + 2 < n) ? cnt[base + 2] : 0;
    int v3 = (base + 3 < n) ? cnt[base + 3] : 0;
    int tsum = v0 + v1 + v2 + v3;
    lds[tid] = tsum;
    __syncthreads();
    for (int off = 1; off < 256; off <<= 1) {
        int t = (tid >= off) ? lds[tid - off] : 0;
        __syncthreads();
        lds[tid] += t;
        __syncthreads();
    }
    int excl = lds[tid] - tsum;
    if (tid == 255) bsum[blockIdx.x] = lds[255];
    int run = excl;
    if (base + 0 < n) { offs[base + 0] = run; } run += v0;
    if (base + 1 < n) { offs[base + 1] = run; } run += v1;
    if (base + 2 < n) { offs[base + 2] = run; } run += v2;
    if (base + 3 < n) { offs[base + 3] = run; }
}

// adds block bases (re-scans <=256 block sums in-block), writes cursor + dinv
__global__ void scan_add_k(const int* __restrict__ cnt, int* __restrict__ offs,
                           const int* __restrict__ bsum, int nb,
                           int* __restrict__ cursor, float* __restrict__ dinv,
                           int n, int Etot) {
    __shared__ int lds[256];
    int tid = threadIdx.x;
    int v = (tid < nb) ? bsum[tid] : 0;
    lds[tid] = v;
    __syncthreads();
    for (int off = 1; off < 256; off <<= 1) {
        int t = (tid >= off) ? lds[tid - off] : 0;
        __syncthreads();
        lds[tid] += t;
        __syncthreads();
    }
    int excl = lds[tid] - v;
    __syncthreads();
    lds[tid] = excl;
    __syncthreads();

    int i = blockIdx.x * blockDim.x + tid;
    if (i < n) {
        int o = offs[i] + lds[i >> 10];
        offs[i] = o;
        cursor[i] = o;
        dinv[i] = rsqrtf((float)cnt[i] + 1.0f);   // +1 for self-loop
    }
    if (i == 0) offs[n] = Etot;
}

// ---------------- CSR fill (XCD-ownership) + x padding, fused ----------------
__global__ void fillpad_k(const int* __restrict__ row, const int* __restrict__ col,
                          const float* __restrict__ dinv, int* __restrict__ cursor,
                          int2* __restrict__ srcw, int E, int N,
                          const float* __restrict__ x, float* __restrict__ xp,
                          int INR, int padTot) {
    int bid = blockIdx.x, tid = threadIdx.x;
    int pidx = bid * 256 + tid;
    if (pidx < padTot) {
        int i = pidx >> 5, k = pidx & 31;
        xp[pidx] = (k < INR) ? x[i * INR + k] : 0.f;
    }
    int xcd = bid & 7;
    int chunk = bid >> 3;
    int e = chunk * 256 + tid;
    if (e >= E) return;
    int c = col[e];
    int owner = (int)(((unsigned long long)c * 8ull) / (unsigned)N);
    if (owner != xcd) return;
    int r = row[e];
    float w = dinv[r] * dinv[c];
    int pos = atomicAdd(&cursor[c], 1);
    srcw[pos] = make_int2(r, __float_as_int(w));
}

// ---------------- fused conv (R7-proven structure, dtype-templated) ----------------
// 1 wave/block, MNODES nodes serial, lane = output feature.
// INBF: gather features stored bf16 (128 B rows) — halves the pattern-BW-bound
// fetch traffic. All arithmetic f32. OUTBF: store bf16 RNE.
template <int KIN, bool INBF, bool OUTBF>
__global__ __launch_bounds__(64) void conv_k(
    const void* __restrict__ hin_, const int* __restrict__ offs,
    const int2* __restrict__ srcw, const float* __restrict__ dinv,
    const float* __restrict__ W, int KINR,
    const float* __restrict__ bias, const float* __restrict__ g,
    const float* __restrict__ bb, const float* __restrict__ m,
    const float* __restrict__ v, void* __restrict__ hout_, int n) {
    const float* hf = (const float*)hin_;
    const u16*   hb = (const u16*)hin_;
    int lane = threadIdx.x;
    float wreg[KIN];
#pragma unroll
    for (int k = 0; k < KIN; k++) wreg[k] = (k < KINR) ? W[k * HDIM + lane] : 0.f;
    const float sc = g[lane] * rsqrtf(v[lane] + EPSBN);
    const float sh = (bias[lane] - m[lane]) * sc + bb[lane];

    __shared__ float agg[KIN];

    auto ldh = [&](int node) -> float {
        if (INBF) return bf2f(hb[(size_t)node * KIN + lane]);
        return (lane < KIN) ? hf[(size_t)node * KIN + lane] : 0.f;
    };

    int i0 = blockIdx.x * MNODES;
    for (int j = 0; j < MNODES; j++) {
        int i = i0 + j;
        if (i >= n) break;                  // wave-uniform
        float di = dinv[i];
        float acc = ldh(i) * (di * di);     // self-loop
        int e = offs[i], s1 = offs[i + 1];
        for (; e + 8 <= s1; e += 8) {
            int2 sw0 = srcw[e],     sw1 = srcw[e + 1], sw2 = srcw[e + 2], sw3 = srcw[e + 3];
            int2 sw4 = srcw[e + 4], sw5 = srcw[e + 5], sw6 = srcw[e + 6], sw7 = srcw[e + 7];
            float h0 = ldh(sw0.x), h1 = ldh(sw1.x), h2 = ldh(sw2.x), h3 = ldh(sw3.x);
            float h4 = ldh(sw4.x), h5 = ldh(sw5.x), h6 = ldh(sw6.x), h7 = ldh(sw7.x);
            acc = fmaf(__int_as_float(sw0.y), h0, acc);
            acc = fmaf(__int_as_float(sw1.y), h1, acc);
            acc = fmaf(__int_as_float(sw2.y), h2, acc);
            acc = fmaf(__int_as_float(sw3.y), h3, acc);
            acc = fmaf(__int_as_float(sw4.y), h4, acc);
            acc = fmaf(__int_as_float(sw5.y), h5, acc);
            acc = fmaf(__int_as_float(sw6.y), h6, acc);
            acc = fmaf(__int_as_float(sw7.y), h7, acc);
        }
        for (; e + 4 <= s1; e += 4) {
            int2 sw0 = srcw[e], sw1 = srcw[e + 1], sw2 = srcw[e + 2], sw3 = srcw[e + 3];
            float h0 = ldh(sw0.x), h1 = ldh(sw1.x), h2 = ldh(sw2.x), h3 = ldh(sw3.x);
            acc = fmaf(__int_as_float(sw0.y), h0, acc);
            acc = fmaf(__int_as_float(sw1.y), h1, acc);
            acc = fmaf(__int_as_float(sw2.y), h2, acc);
            acc = fmaf(__int_as_float(sw3.y), h3, acc);
        }
        for (; e < s1; e++) {
            int2 sw = srcw[e];
            acc = fmaf(__int_as_float(sw.y), ldh(sw.x), acc);
        }
        __syncthreads();                    // protect agg from previous iteration readers
        if (lane < KIN) agg[lane] = acc;
        __syncthreads();
        float dot = 0.f;
        const float4* aggv = (const float4*)agg;
#pragma unroll
        for (int k4 = 0; k4 < KIN / 4; k4++) {
            float4 a = aggv[k4];
            dot = fmaf(a.x, wreg[4 * k4 + 0], dot);
            dot = fmaf(a.y, wreg[4 * k4 + 1], dot);
            dot = fmaf(a.z, wreg[4 * k4 + 2], dot);
            dot = fmaf(a.w, wreg[4 * k4 + 3], dot);
        }
        float y = fmaxf(fmaf(dot, sc, sh), 0.f);
        if (OUTBF) ((u16*)hout_)[(size_t)i * HDIM + lane] = f2bf_rne(y);
        else       ((float*)hout_)[(size_t)i * HDIM + lane] = y;
    }
}

// ---------------- pooling (4 waves per graph) + 2-layer MLP ----------------
__global__ __launch_bounds__(256) void pool_mlp_k(
    const float* __restrict__ h, const int* __restrict__ batch,
    const float* __restrict__ Wc1, const float* __restrict__ bc1,
    const float* __restrict__ Wc2, const float* __restrict__ bc2,
    float* __restrict__ out, int n) {
    int gidx = blockIdx.x;
    int tid = threadIdx.x;
    int lane = tid & 63;
    int wv = tid >> 6;

    int lo = 0, hi = n;
    while (lo < hi) { int mid = (lo + hi) >> 1; if (batch[mid] < gidx) lo = mid + 1; else hi = mid; }
    int start = lo;
    lo = start; hi = n;
    while (lo < hi) { int mid = (lo + hi) >> 1; if (batch[mid] <= gidx) lo = mid + 1; else hi = mid; }
    int end = lo;

    float sum = 0.f, mx = 0.f;   // h >= 0 post-ReLU
    for (int i = start + wv; i < end; i += 4) {
        float val = h[(size_t)i * HDIM + lane];
        sum += val;
        mx = fmaxf(mx, val);
    }
    __shared__ float ssum[4 * HDIM];
    __shared__ float smax[4 * HDIM];
    __shared__ float pooled[2 * HDIM];
    ssum[wv * HDIM + lane] = sum;
    smax[wv * HDIM + lane] = mx;
    __syncthreads();
    if (wv == 0) {
        float sv = ssum[lane] + ssum[64 + lane] + ssum[128 + lane] + ssum[192 + lane];
        float mm = fmaxf(fmaxf(smax[lane], smax[64 + lane]),
                         fmaxf(smax[128 + lane], smax[192 + lane]));
        int cnt = end - start;
        pooled[lane] = sv / fmaxf((float)cnt, 1.f);
        pooled[HDIM + lane] = mm;
    }
    __syncthreads();
    if (wv == 0) {
        float a = bc1[lane];
#pragma unroll
        for (int k = 0; k < 2 * HDIM; k++) a = fmaf(pooled[k], Wc1[k * HDIM + lane], a);
        a = fmaxf(a, 0.f);
#pragma unroll
        for (int c = 0; c < 2; c++) {
            float vv = a * Wc2[lane * 2 + c];
            for (int off = 32; off; off >>= 1) vv += __shfl_down(vv, off);
            if (lane == 0) out[gidx * 2 + c] = vv + bc2[c];
        }
    }
}

extern "C" void kernel_launch(void* const* d_in, const int* in_sizes, int n_in,
                              void* d_out, int out_size, void* d_ws, size_t ws_size,
                              hipStream_t stream) {
    const float* x    = (const float*)d_in[0];
    const int*   erow = (const int*)d_in[1];
    const int*   ecol = (const int*)d_in[2];
    const int*   batch= (const int*)d_in[3];
    const float* W0   = (const float*)d_in[4];
    const float* b0   = (const float*)d_in[5];
    const float* W1   = (const float*)d_in[6];
    const float* b1   = (const float*)d_in[7];
    const float* W2   = (const float*)d_in[8];
    const float* b2   = (const float*)d_in[9];
    const float* bn_g = (const float*)d_in[10];
    const float* bn_b = (const float*)d_in[11];
    const float* bn_m = (const float*)d_in[12];
    const float* bn_v = (const float*)d_in[13];
    const float* Wc1  = (const float*)d_in[14];
    const float* bc1  = (const float*)d_in[15];
    const float* Wc2  = (const float*)d_in[16];
    const float* bc2  = (const float*)d_in[17];
    float* out = (float*)d_out;

    const int N = in_sizes[3];
    const int E = in_sizes[1];
    const int G = out_size / 2;
    const int INR = in_sizes[0] / N;    // 26

    char* ws = (char*)d_ws;
    size_t off = 0;
    auto alloc = [&](size_t bytes) -> void* {
        void* p = ws + off;
        off += (bytes + 255) & ~(size_t)255;
        return p;
    };
    int*   cnt    = (int*)alloc((size_t)N * 4);
    float* dinv   = (float*)alloc((size_t)N * 4);
    int*   offs   = (int*)alloc((size_t)(N + 1) * 4);
    int*   cursor = (int*)alloc((size_t)N * 4);
    int*   bsum   = (int*)alloc(1024);
    int2*  srcw   = (int2*)alloc((size_t)E * 8 + 256);
    void*  bufA   = alloc((size_t)N * HDIM * 4);   // h1 (bf16) then h3 (f32)
    void*  bufB   = alloc((size_t)N * HDIM * 4);   // xp (f32 [N][32]) then h2 (bf16)
    (void)ws_size;

    // ---- build gcn_norm + CSR transpose ----
    hipMemsetAsync(cnt, 0, (size_t)N * 4, stream);
    count_edges_k<<<(E + 255) / 256, 256, 0, stream>>>(ecol, cnt, E);
    int nb = (N + 1023) / 1024;
    scan_partial_k<<<nb, 256, 0, stream>>>(cnt, offs, bsum, N);
    scan_add_k<<<(N + 255) / 256, 256, 0, stream>>>(cnt, offs, bsum, nb, cursor, dinv, N, E);
    int chunks = (E + 255) / 256;
    fillpad_k<<<chunks * 8, 256, 0, stream>>>(erow, ecol, dinv, cursor, srcw, E, N,
                                              x, (float*)bufB, INR, N * 32);

    int cgrid = (N + MNODES - 1) / MNODES;
    // ---- layer 0: xp f32 [N][32] -> h1 bf16 ----
    conv_k<32, false, true><<<cgrid, 64, 0, stream>>>(bufB, offs, srcw, dinv, W0, INR, b0,
        bn_g + 0, bn_b + 0, bn_m + 0, bn_v + 0, bufA, N);
    // ---- layer 1: h1 bf16 -> h2 bf16 ----
    conv_k<64, true, true><<<cgrid, 64, 0, stream>>>(bufA, offs, srcw, dinv, W1, 64, b1,
        bn_g + 64, bn_b + 64, bn_m + 64, bn_v + 64, bufB, N);
    // ---- layer 2: h2 bf16 -> h3 f32 ----
    conv_k<64, true, false><<<cgrid, 64, 0, stream>>>(bufB, offs, srcw, dinv, W2, 64, b2,
        bn_g + 128, bn_b + 128, bn_m + 128, bn_v + 128, bufA, N);

    // ---- pool + MLP ----
    pool_mlp_k<<<G, 256, 0, stream>>>((const float*)bufA, batch, Wc1, bc1, Wc2, bc2, out, N);
}